// Round 2
// baseline (232.635 us; speedup 1.0000x reference)
//
#include <hip/hip_runtime.h>

#define N_NODES   8192
#define N_EDGES   65536
#define IN_DIM    768
#define HIDDEN    4096
#define N_CLASSES 16

typedef unsigned short ushort_t;
typedef __attribute__((ext_vector_type(8))) short bf16x8;
typedef __attribute__((ext_vector_type(4))) float f32x4;

__device__ __forceinline__ ushort_t f2bf(float f) {
    union { float f; unsigned i; } v; v.f = f;
    unsigned r = v.i + 0x7FFFu + ((v.i >> 16) & 1u);   // RNE
    return (ushort_t)(r >> 16);
}
__device__ __forceinline__ float bf2f(ushort_t u) {
    union { unsigned i; float f; } v; v.i = ((unsigned)u) << 16; return v.f;
}

#define GLD_LDS16(gp, lp) \
    __builtin_amdgcn_global_load_lds((const __attribute__((address_space(1))) void*)(gp), \
                                     (__attribute__((address_space(3))) void*)(lp), 16, 0, 0)

// ---------------- edge-index layout probe ----------------
// int32 layout: ei32[2e+1] are edge values (nonzero w.h.p. over 4096 samples).
// int64 layout: ei32[2e+1] are high words == 0 (values < 8192).
__global__ __launch_bounds__(256) void detect_layout(const int* __restrict__ ei, int* __restrict__ flag) {
    int v = 0;
    for (int e = threadIdx.x; e < 4096; e += 256) v |= ei[2 * e + 1];
    if (v) atomicOr(flag, 1);
}

__device__ __forceinline__ int esrc(const int* ei, int f32mode, int e) {
    return f32mode ? ei[e] : ei[2 * e];
}
__device__ __forceinline__ int edst(const int* ei, int f32mode, int e) {
    return f32mode ? ei[N_EDGES + e] : ei[2 * N_EDGES + 2 * e];
}

// ---------------- setup kernels ----------------

// W1 fp32 [768][4096] -> W1T bf16 [4096][768]
__global__ __launch_bounds__(256) void transpose_w1(const float* __restrict__ W1,
                                                    ushort_t* __restrict__ W1T) {
    __shared__ ushort_t tile[32][33];
    int n0 = blockIdx.x * 32, k0 = blockIdx.y * 32;
    int tx = threadIdx.x & 31, ty = threadIdx.x >> 5;  // ty: 0..7
    #pragma unroll
    for (int j = 0; j < 4; j++) {
        int k = ty * 4 + j;
        tile[k][tx] = f2bf(W1[(k0 + k) * HIDDEN + n0 + tx]);
    }
    __syncthreads();
    #pragma unroll
    for (int j = 0; j < 4; j++) {
        int n = ty * 4 + j;
        W1T[(n0 + n) * IN_DIM + k0 + tx] = tile[tx][n];
    }
}

// W2 fp32 [4096][16] -> W2T bf16 [16][4096]
__global__ __launch_bounds__(256) void transpose_w2(const float* __restrict__ W2,
                                                    ushort_t* __restrict__ W2T) {
    int idx = blockIdx.x * 256 + threadIdx.x;          // 65536
    int c = idx & 15, k = idx >> 4;
    W2T[c * HIDDEN + k] = f2bf(W2[idx]);
}

__global__ __launch_bounds__(256) void init_deg(int* __restrict__ deg, int* __restrict__ cursor,
                                                int* __restrict__ flag) {
    int i = blockIdx.x * 256 + threadIdx.x;
    deg[i] = 1;          // self-loop
    cursor[i] = 0;
    if (i == 0) *flag = 0;
}

__global__ __launch_bounds__(256) void count_deg(const int* __restrict__ ei, int* __restrict__ deg,
                                                 const int* __restrict__ flag) {
    int e = blockIdx.x * 256 + threadIdx.x;            // 65536
    int f = *flag;
    atomicAdd(&deg[edst(ei, f, e)], 1);
}

// exclusive scan of (deg-1) over 8192 nodes; also dinv = rsqrt(deg)
__global__ __launch_bounds__(1024) void scan_offs(const int* __restrict__ deg,
                                                  int* __restrict__ offs,
                                                  float* __restrict__ dinv) {
    __shared__ int part[1024];
    int t = threadIdx.x;
    int base = t * 8;
    int c[8]; int s = 0;
    #pragma unroll
    for (int j = 0; j < 8; j++) {
        int d = deg[base + j];
        dinv[base + j] = rsqrtf((float)d);
        c[j] = d - 1;
        s += c[j];
    }
    part[t] = s;
    __syncthreads();
    for (int off = 1; off < 1024; off <<= 1) {
        int v = part[t];
        int add = (t >= off) ? part[t - off] : 0;
        __syncthreads();
        part[t] = v + add;
        __syncthreads();
    }
    int run = part[t] - s;   // exclusive base
    #pragma unroll
    for (int j = 0; j < 8; j++) { offs[base + j] = run; run += c[j]; }
}

__global__ __launch_bounds__(256) void scatter_edges(const int* __restrict__ ei,
                                                     const int* __restrict__ offs,
                                                     int* __restrict__ cursor,
                                                     int* __restrict__ elist,
                                                     const int* __restrict__ flag) {
    int e = blockIdx.x * 256 + threadIdx.x;            // 65536
    int f = *flag;
    int s = esrc(ei, f, e), d = edst(ei, f, e);
    int p = atomicAdd(&cursor[d], 1);
    elist[offs[d] + p] = s;
}

// xagg[d] = dinv[d] * ( sum_{e:dst=d} dinv[src]*x[src] + dinv[d]*x[d] ), stored bf16
__global__ __launch_bounds__(256) void aggregate(const float* __restrict__ x,
                                                 const int* __restrict__ offs,
                                                 const int* __restrict__ deg,
                                                 const int* __restrict__ elist,
                                                 const float* __restrict__ dinv,
                                                 ushort_t* __restrict__ xagg) {
    int d = blockIdx.x;
    int t = threadIdx.x;
    float wd = dinv[d];
    const float* xd = x + (long)d * IN_DIM;
    float a0 = wd * xd[t];
    float a1 = wd * xd[t + 256];
    float a2 = wd * xd[t + 512];
    int cnt = deg[d] - 1, base = offs[d];
    for (int j = 0; j < cnt; j++) {
        int s = elist[base + j];
        float ws = dinv[s];
        const float* xs = x + (long)s * IN_DIM;
        a0 += ws * xs[t];
        a1 += ws * xs[t + 256];
        a2 += ws * xs[t + 512];
    }
    ushort_t* o = xagg + (long)d * IN_DIM;
    o[t]       = f2bf(a0 * wd);
    o[t + 256] = f2bf(a1 * wd);
    o[t + 512] = f2bf(a2 * wd);
}

// ---------------- GEMM1: [8192,768] @ [768,4096] (B as W1T bf16 [4096,768]) ----------------
// 128x128 tile, BK=32, 4 waves each 64x64 (4x4 of 16x16x32 MFMA), global_load_lds width 16.
__global__ __launch_bounds__(256) void gemm1(const ushort_t* __restrict__ A,   // xagg bf16
                                             const ushort_t* __restrict__ Bt,  // W1T bf16
                                             const float* __restrict__ b1,
                                             ushort_t* __restrict__ H) {
    __shared__ ushort_t ldsA[128 * 32];
    __shared__ ushort_t ldsB[128 * 32];
    int bx = blockIdx.x & 31;          // n tile  (4096/128 = 32)
    int by = blockIdx.x >> 5;          // m tile  (8192/128 = 64)
    int m0 = by * 128, n0 = bx * 128;
    int t = threadIdx.x;
    int w = t >> 6, l = t & 63;
    int wm = w & 1, wn = w >> 1;
    int q = l >> 4, lm = l & 15;

    f32x4 acc[4][4] = {};

    const ushort_t* Ag = A + (long)m0 * IN_DIM;
    const ushort_t* Bg = Bt + (long)n0 * IN_DIM;

    for (int ks = 0; ks < IN_DIM; ks += 32) {
        __syncthreads();
        #pragma unroll
        for (int i = 0; i < 2; i++) {
            int L = i * 256 + t;
            int row = L >> 2, c16 = L & 3;
            GLD_LDS16(Ag + row * IN_DIM + ks + c16 * 8, ldsA + (i * 256 + w * 64) * 8);
            GLD_LDS16(Bg + row * IN_DIM + ks + c16 * 8, ldsB + (i * 256 + w * 64) * 8);
        }
        __syncthreads();

        bf16x8 af[4], bfr[4];
        #pragma unroll
        for (int mt = 0; mt < 4; mt++) {
            int m = wm * 64 + mt * 16 + lm;
            af[mt] = *(const bf16x8*)(ldsA + m * 32 + q * 8);
        }
        #pragma unroll
        for (int nt = 0; nt < 4; nt++) {
            int n = wn * 64 + nt * 16 + lm;
            bfr[nt] = *(const bf16x8*)(ldsB + n * 32 + q * 8);
        }
        #pragma unroll
        for (int mt = 0; mt < 4; mt++)
            #pragma unroll
            for (int nt = 0; nt < 4; nt++)
                acc[mt][nt] = __builtin_amdgcn_mfma_f32_16x16x32_bf16(af[mt], bfr[nt], acc[mt][nt], 0, 0, 0);
    }

    // epilogue: +b1, ReLU, bf16 store.  C layout: col=lane&15, row=(lane>>4)*4+reg
    #pragma unroll
    for (int nt = 0; nt < 4; nt++) {
        int col = n0 + wn * 64 + nt * 16 + lm;
        float bias = b1[col];
        #pragma unroll
        for (int mt = 0; mt < 4; mt++) {
            #pragma unroll
            for (int r = 0; r < 4; r++) {
                int row = m0 + wm * 64 + mt * 16 + q * 4 + r;
                float v = acc[mt][nt][r] + bias;
                v = v > 0.0f ? v : 0.0f;
                H[(long)row * HIDDEN + col] = f2bf(v);
            }
        }
    }
}

// ---------------- GEMM2 + log_softmax: [8192,4096] @ [4096,16], fp32 out ----------------
__global__ __launch_bounds__(256) void gemm2_softmax(const ushort_t* __restrict__ H,
                                                     const ushort_t* __restrict__ W2T,
                                                     const float* __restrict__ b2,
                                                     float* __restrict__ out) {
    int t = threadIdx.x;
    int w = t >> 6, l = t & 63;
    int q = l >> 4, m = l & 15;
    int row0 = blockIdx.x * 64 + w * 16;

    const ushort_t* hrow = H + (long)(row0 + m) * HIDDEN;  // A: m = lane&15
    const ushort_t* wrow = W2T + (long)m * HIDDEN;         // B: n = lane&15

    f32x4 acc = {};
    for (int k = 0; k < HIDDEN; k += 32) {
        bf16x8 a = *(const bf16x8*)(hrow + k + q * 8);
        bf16x8 b = *(const bf16x8*)(wrow + k + q * 8);
        acc = __builtin_amdgcn_mfma_f32_16x16x32_bf16(a, b, acc, 0, 0, 0);
    }

    float bias = b2[m];   // col = m
    #pragma unroll
    for (int r = 0; r < 4; r++) {
        float v = acc[r] + bias;                 // logits[row0+q*4+r][m]
        float mx = v;
        #pragma unroll
        for (int off = 1; off < 16; off <<= 1)
            mx = fmaxf(mx, __shfl_xor(mx, off, 64));
        float e = __expf(v - mx);
        float s = e;
        #pragma unroll
        for (int off = 1; off < 16; off <<= 1)
            s += __shfl_xor(s, off, 64);
        float res = v - mx - __logf(s);
        out[(long)(row0 + q * 4 + r) * N_CLASSES + m] = res;
    }
}

// ---------------- launch ----------------

extern "C" void kernel_launch(void* const* d_in, const int* in_sizes, int n_in,
                              void* d_out, int out_size, void* d_ws, size_t ws_size,
                              hipStream_t stream) {
    const float* x  = (const float*)d_in[0];
    const int*   ei = (const int*)d_in[1];
    const float* W1 = (const float*)d_in[2];
    const float* b1 = (const float*)d_in[3];
    const float* W2 = (const float*)d_in[4];
    const float* b2 = (const float*)d_in[5];
    float* out = (float*)d_out;
    char* ws = (char*)d_ws;

    ushort_t* h2   = (ushort_t*)(ws);                        // 8192*4096*2 = 67108864
    ushort_t* xagg = (ushort_t*)(ws + 67108864);             // 8192*768*2  = 12582912
    ushort_t* W1T  = (ushort_t*)(ws + 79691776);             // 4096*768*2  =  6291456
    ushort_t* W2T  = (ushort_t*)(ws + 85983232);             // 16*4096*2   =   131072
    int*      deg    = (int*)(ws + 86114304);                // 8192*4
    float*    dinv   = (float*)(ws + 86147072);              // 8192*4
    int*      offs   = (int*)(ws + 86179840);                // 8192*4
    int*      cursor = (int*)(ws + 86212608);                // 8192*4
    int*      elist  = (int*)(ws + 86245376);                // 65536*4
    int*      flag   = (int*)(ws + 86507520);                // 4

    init_deg<<<N_NODES / 256, 256, 0, stream>>>(deg, cursor, flag);
    detect_layout<<<1, 256, 0, stream>>>(ei, flag);
    transpose_w1<<<dim3(HIDDEN / 32, IN_DIM / 32), 256, 0, stream>>>(W1, W1T);
    transpose_w2<<<(HIDDEN * N_CLASSES) / 256, 256, 0, stream>>>(W2, W2T);
    count_deg<<<N_EDGES / 256, 256, 0, stream>>>(ei, deg, flag);
    scan_offs<<<1, 1024, 0, stream>>>(deg, offs, dinv);
    scatter_edges<<<N_EDGES / 256, 256, 0, stream>>>(ei, offs, cursor, elist, flag);
    aggregate<<<N_NODES, 256, 0, stream>>>(x, offs, deg, elist, dinv, xagg);
    gemm1<<<(N_NODES / 128) * (HIDDEN / 128), 256, 0, stream>>>(xagg, W1T, b1, h2);
    gemm2_softmax<<<N_NODES / 64, 256, 0, stream>>>(h2, W2T, b2, out);
}

// Round 3
// 209.333 us; speedup vs baseline: 1.1113x; 1.1113x over previous
//
#include <hip/hip_runtime.h>

#define N_NODES   8192
#define N_EDGES   65536
#define IN_DIM    768
#define HIDDEN    4096
#define N_CLASSES 16

typedef unsigned short ushort_t;
typedef __attribute__((ext_vector_type(8))) short bf16x8;
typedef __attribute__((ext_vector_type(4))) float f32x4;

__device__ __forceinline__ ushort_t f2bf(float f) {
    union { float f; unsigned i; } v; v.f = f;
    unsigned r = v.i + 0x7FFFu + ((v.i >> 16) & 1u);   // RNE
    return (ushort_t)(r >> 16);
}

#define GLD_LDS16(gp, lp) \
    __builtin_amdgcn_global_load_lds((const __attribute__((address_space(1))) void*)(gp), \
                                     (__attribute__((address_space(3))) void*)(lp), 16, 0, 0)

__device__ __forceinline__ int esrc(const int* ei, int f32mode, int e) {
    return f32mode ? ei[e] : ei[2 * e];
}
__device__ __forceinline__ int edst(const int* ei, int f32mode, int e) {
    return f32mode ? ei[N_EDGES + e] : ei[2 * N_EDGES + 2 * e];
}

// ---------------- K1: W2 transpose + deg/cursor init + edge-layout detect ----------------
// blocks 0..255: W2 [4096][16] fp32 -> W2T bf16 [16][4096]
// blocks 256..287: deg=1 (self-loop), cursor=0
// block 288: detect int32-vs-int64 edge layout -> flag (no atomics, single writer)
__global__ __launch_bounds__(256) void setup1(const float* __restrict__ W2,
                                              ushort_t* __restrict__ W2T,
                                              int* __restrict__ deg, int* __restrict__ cursor,
                                              const int* __restrict__ ei, int* __restrict__ flag) {
    int b = blockIdx.x, t = threadIdx.x;
    if (b < 256) {
        int idx = b * 256 + t;                 // 65536
        int c = idx & 15, k = idx >> 4;
        W2T[c * HIDDEN + k] = f2bf(W2[idx]);
    } else if (b < 288) {
        int i = (b - 256) * 256 + t;           // 8192
        deg[i] = 1;
        cursor[i] = 0;
    } else {
        // int32 layout: odd words are real edge values (not all zero over 4096 samples).
        // int64 layout: odd words are high halves of values < 8192 -> all zero.
        __shared__ int sv[256];
        int v = 0;
        for (int e = t; e < 4096; e += 256) v |= ei[2 * e + 1];
        sv[t] = v;
        __syncthreads();
        for (int off = 128; off > 0; off >>= 1) {
            if (t < off) sv[t] |= sv[t + off];
            __syncthreads();
        }
        if (t == 0) *flag = (sv[0] != 0) ? 1 : 0;
    }
}

// ---------------- K2: W1 transpose + degree count ----------------
// blocks 0..3071: W1 fp32 [768][4096] -> W1T bf16 [4096][768]
// blocks 3072..3327: count in-degrees
__global__ __launch_bounds__(256) void setup2(const float* __restrict__ W1,
                                              ushort_t* __restrict__ W1T,
                                              const int* __restrict__ ei, int* __restrict__ deg,
                                              const int* __restrict__ flag) {
    int b = blockIdx.x, t = threadIdx.x;
    if (b < 3072) {
        __shared__ ushort_t tile[32][33];
        int n0 = (b & 127) * 32, k0 = (b >> 7) * 32;
        int tx = t & 31, ty = t >> 5;          // ty: 0..7
        #pragma unroll
        for (int j = 0; j < 4; j++) {
            int k = ty * 4 + j;
            tile[k][tx] = f2bf(W1[(k0 + k) * HIDDEN + n0 + tx]);
        }
        __syncthreads();
        #pragma unroll
        for (int j = 0; j < 4; j++) {
            int n = ty * 4 + j;
            W1T[(n0 + n) * IN_DIM + k0 + tx] = tile[tx][n];
        }
    } else {
        int e = (b - 3072) * 256 + t;          // 65536
        int f = *flag;
        atomicAdd(&deg[edst(ei, f, e)], 1);
    }
}

// exclusive scan of (deg-1) over 8192 nodes; also dinv = rsqrt(deg)
__global__ __launch_bounds__(1024) void scan_offs(const int* __restrict__ deg,
                                                  int* __restrict__ offs,
                                                  float* __restrict__ dinv) {
    __shared__ int part[1024];
    int t = threadIdx.x;
    int base = t * 8;
    int c[8]; int s = 0;
    #pragma unroll
    for (int j = 0; j < 8; j++) {
        int d = deg[base + j];
        dinv[base + j] = rsqrtf((float)d);
        c[j] = d - 1;
        s += c[j];
    }
    part[t] = s;
    __syncthreads();
    for (int off = 1; off < 1024; off <<= 1) {
        int v = part[t];
        int add = (t >= off) ? part[t - off] : 0;
        __syncthreads();
        part[t] = v + add;
        __syncthreads();
    }
    int run = part[t] - s;   // exclusive base
    #pragma unroll
    for (int j = 0; j < 8; j++) { offs[base + j] = run; run += c[j]; }
}

__global__ __launch_bounds__(256) void scatter_edges(const int* __restrict__ ei,
                                                     const int* __restrict__ offs,
                                                     int* __restrict__ cursor,
                                                     int* __restrict__ elist,
                                                     const int* __restrict__ flag) {
    int e = blockIdx.x * 256 + threadIdx.x;            // 65536
    int f = *flag;
    int s = esrc(ei, f, e), d = edst(ei, f, e);
    int p = atomicAdd(&cursor[d], 1);
    elist[offs[d] + p] = s;
}

// one wave per node; float4 gather; xagg = dinv[d]*(sum dinv[s]*x[s] + dinv[d]*x[d]) -> bf16
__global__ __launch_bounds__(256) void aggregate(const float* __restrict__ x,
                                                 const int* __restrict__ offs,
                                                 const int* __restrict__ deg,
                                                 const int* __restrict__ elist,
                                                 const float* __restrict__ dinv,
                                                 ushort_t* __restrict__ xagg) {
    int wv = threadIdx.x >> 6, l = threadIdx.x & 63;
    int d = blockIdx.x * 4 + wv;
    float wd = dinv[d];
    const float4* xd = (const float4*)(x + (long)d * IN_DIM);   // 192 float4/row
    float4 a0 = xd[l], a1 = xd[l + 64], a2 = xd[l + 128];
    a0.x *= wd; a0.y *= wd; a0.z *= wd; a0.w *= wd;
    a1.x *= wd; a1.y *= wd; a1.z *= wd; a1.w *= wd;
    a2.x *= wd; a2.y *= wd; a2.z *= wd; a2.w *= wd;
    int cnt = deg[d] - 1, base = offs[d];
    for (int j = 0; j < cnt; j++) {
        int s = elist[base + j];
        float ws = dinv[s];
        const float4* xs = (const float4*)(x + (long)s * IN_DIM);
        float4 v0 = xs[l], v1 = xs[l + 64], v2 = xs[l + 128];
        a0.x = fmaf(ws, v0.x, a0.x); a0.y = fmaf(ws, v0.y, a0.y);
        a0.z = fmaf(ws, v0.z, a0.z); a0.w = fmaf(ws, v0.w, a0.w);
        a1.x = fmaf(ws, v1.x, a1.x); a1.y = fmaf(ws, v1.y, a1.y);
        a1.z = fmaf(ws, v1.z, a1.z); a1.w = fmaf(ws, v1.w, a1.w);
        a2.x = fmaf(ws, v2.x, a2.x); a2.y = fmaf(ws, v2.y, a2.y);
        a2.z = fmaf(ws, v2.z, a2.z); a2.w = fmaf(ws, v2.w, a2.w);
    }
    ushort4* o = (ushort4*)(xagg + (long)d * IN_DIM);
    ushort4 r0 = { f2bf(a0.x * wd), f2bf(a0.y * wd), f2bf(a0.z * wd), f2bf(a0.w * wd) };
    ushort4 r1 = { f2bf(a1.x * wd), f2bf(a1.y * wd), f2bf(a1.z * wd), f2bf(a1.w * wd) };
    ushort4 r2 = { f2bf(a2.x * wd), f2bf(a2.y * wd), f2bf(a2.z * wd), f2bf(a2.w * wd) };
    o[l] = r0; o[l + 64] = r1; o[l + 128] = r2;
}

// ---------------- fused GEMM1 + ReLU + partial GEMM2 ----------------
// H_tile = relu(xagg@W1T + b1) [128x128 per block, in regs] then
// part[bx*2+wn] += H_tile @ W2T-slice (per-wave 64x64 LDS transpose -> 8 MFMAs).
__global__ __launch_bounds__(256) void gemm1_fused(const ushort_t* __restrict__ A,   // xagg bf16
                                                   const ushort_t* __restrict__ Bt,  // W1T bf16
                                                   const float* __restrict__ b1,
                                                   const ushort_t* __restrict__ W2T, // bf16 [16][4096]
                                                   float* __restrict__ part) {       // [64][8192][16]
    __shared__ char smem[40960];
    ushort_t* ldsA = (ushort_t*)smem;              // 128x32 bf16 = 8 KB
    ushort_t* ldsB = (ushort_t*)(smem + 8192);     // 8 KB
    int bx = blockIdx.x & 31;          // n tile  (4096/128 = 32)
    int by = blockIdx.x >> 5;          // m tile  (8192/128 = 64)
    int m0 = by * 128, n0 = bx * 128;
    int t = threadIdx.x;
    int w = t >> 6, l = t & 63;
    int wm = w & 1, wn = w >> 1;
    int q = l >> 4, lm = l & 15;

    f32x4 acc[4][4] = {};

    const ushort_t* Ag = A + (long)m0 * IN_DIM;
    const ushort_t* Bg = Bt + (long)n0 * IN_DIM;

    for (int ks = 0; ks < IN_DIM; ks += 32) {
        __syncthreads();
        #pragma unroll
        for (int i = 0; i < 2; i++) {
            int L = i * 256 + t;
            int row = L >> 2, c16 = L & 3;
            GLD_LDS16(Ag + row * IN_DIM + ks + c16 * 8, ldsA + (i * 256 + w * 64) * 8);
            GLD_LDS16(Bg + row * IN_DIM + ks + c16 * 8, ldsB + (i * 256 + w * 64) * 8);
        }
        __syncthreads();

        bf16x8 af[4], bfr[4];
        #pragma unroll
        for (int mt = 0; mt < 4; mt++)
            af[mt] = *(const bf16x8*)(ldsA + (wm * 64 + mt * 16 + lm) * 32 + q * 8);
        #pragma unroll
        for (int nt = 0; nt < 4; nt++)
            bfr[nt] = *(const bf16x8*)(ldsB + (wn * 64 + nt * 16 + lm) * 32 + q * 8);
        #pragma unroll
        for (int mt = 0; mt < 4; mt++)
            #pragma unroll
            for (int nt = 0; nt < 4; nt++)
                acc[mt][nt] = __builtin_amdgcn_mfma_f32_16x16x32_bf16(af[mt], bfr[nt], acc[mt][nt], 0, 0, 0);
    }

    // ---- epilogue: bias+ReLU, C-layout -> A-layout via LDS, x W2T slice ----
    __syncthreads();   // all waves done reading staging LDS before overwrite
    const int RP = 80;                                   // padded row (16B-aligned stride)
    ushort_t* myhl = (ushort_t*)smem + w * 64 * RP;      // per-wave 64x80 bf16 = 10 KB

    float bias[4];
    #pragma unroll
    for (int nt = 0; nt < 4; nt++) bias[nt] = b1[n0 + wn * 64 + nt * 16 + lm];

    #pragma unroll
    for (int mt = 0; mt < 4; mt++) {
        #pragma unroll
        for (int nt = 0; nt < 4; nt++) {
            #pragma unroll
            for (int r = 0; r < 4; r++) {
                float v = acc[mt][nt][r] + bias[nt];
                v = v > 0.0f ? v : 0.0f;
                // C layout: row_local = mt*16 + q*4 + r, col_local = nt*16 + lm
                myhl[(mt * 16 + q * 4 + r) * RP + nt * 16 + lm] = f2bf(v);
            }
        }
    }
    // no barrier: each wave reads only its own slab (lgkmcnt handles raw deps)

    f32x4 acc2[4] = {};
    #pragma unroll
    for (int kk = 0; kk < 2; kk++) {
        // B frag: n = lm (class), k = kk*32 + q*8 + j, contiguous in W2T row
        bf16x8 bf2 = *(const bf16x8*)(W2T + (long)lm * HIDDEN + n0 + wn * 64 + kk * 32 + q * 8);
        #pragma unroll
        for (int mt = 0; mt < 4; mt++) {
            bf16x8 a2 = *(const bf16x8*)(myhl + (mt * 16 + lm) * RP + kk * 32 + q * 8);
            acc2[mt] = __builtin_amdgcn_mfma_f32_16x16x32_bf16(a2, bf2, acc2[mt], 0, 0, 0);
        }
    }

    // store partials: slab = bx*2+wn; C layout: row = q*4+r, col(class) = lm
    float* pslab = part + ((long)(bx * 2 + wn) * N_NODES + m0 + wm * 64) * N_CLASSES;
    #pragma unroll
    for (int mt = 0; mt < 4; mt++)
        #pragma unroll
        for (int r = 0; r < 4; r++)
            pslab[(mt * 16 + q * 4 + r) * N_CLASSES + lm] = acc2[mt][r];
}

// ---------------- reduce 64 slabs + b2 + log_softmax ----------------
__global__ __launch_bounds__(256) void reduce_softmax(const float* __restrict__ part,
                                                      const float* __restrict__ b2,
                                                      float* __restrict__ out) {
    int t = threadIdx.x;
    int row = blockIdx.x * 16 + (t >> 4);
    int cls = t & 15;
    float v = b2[cls];
    #pragma unroll
    for (int s = 0; s < 64; s++)
        v += part[((long)s * N_NODES + row) * N_CLASSES + cls];
    float mx = v;
    #pragma unroll
    for (int off = 1; off < 16; off <<= 1)
        mx = fmaxf(mx, __shfl_xor(mx, off, 64));
    float e = __expf(v - mx);
    float sm = e;
    #pragma unroll
    for (int off = 1; off < 16; off <<= 1)
        sm += __shfl_xor(sm, off, 64);
    out[(long)row * N_CLASSES + cls] = v - mx - __logf(sm);
}

// ---------------- launch ----------------

extern "C" void kernel_launch(void* const* d_in, const int* in_sizes, int n_in,
                              void* d_out, int out_size, void* d_ws, size_t ws_size,
                              hipStream_t stream) {
    const float* x  = (const float*)d_in[0];
    const int*   ei = (const int*)d_in[1];
    const float* W1 = (const float*)d_in[2];
    const float* b1 = (const float*)d_in[3];
    const float* W2 = (const float*)d_in[4];
    const float* b2 = (const float*)d_in[5];
    float* out = (float*)d_out;
    char* ws = (char*)d_ws;

    float*    part = (float*)(ws);                           // 64*8192*16*4 = 33554432
    ushort_t* xagg = (ushort_t*)(ws + 33554432);             // 8192*768*2   = 12582912
    ushort_t* W1T  = (ushort_t*)(ws + 46137344);             // 4096*768*2   =  6291456
    ushort_t* W2T  = (ushort_t*)(ws + 52428800);             // 16*4096*2    =   131072
    int*      deg    = (int*)(ws + 52559872);                // 8192*4
    float*    dinv   = (float*)(ws + 52592640);              // 8192*4
    int*      offs   = (int*)(ws + 52625408);                // 8192*4
    int*      cursor = (int*)(ws + 52658176);                // 8192*4
    int*      elist  = (int*)(ws + 52690944);                // 65536*4
    int*      flag   = (int*)(ws + 52953088);                // 4

    setup1<<<289, 256, 0, stream>>>(W2, W2T, deg, cursor, ei, flag);
    setup2<<<3328, 256, 0, stream>>>(W1, W1T, ei, deg, flag);
    scan_offs<<<1, 1024, 0, stream>>>(deg, offs, dinv);
    scatter_edges<<<N_EDGES / 256, 256, 0, stream>>>(ei, offs, cursor, elist, flag);
    aggregate<<<N_NODES / 4, 256, 0, stream>>>(x, offs, deg, elist, dinv, xagg);
    gemm1_fused<<<(N_NODES / 128) * (HIDDEN / 128), 256, 0, stream>>>(xagg, W1T, b1, W2T, part);
    reduce_softmax<<<N_NODES / 16, 256, 0, stream>>>(part, b2, out);
}

// Round 4
// 186.072 us; speedup vs baseline: 1.2502x; 1.1250x over previous
//
#include <hip/hip_runtime.h>

#define N_NODES   8192
#define N_EDGES   65536
#define IN_DIM    768
#define HIDDEN    4096
#define N_CLASSES 16

typedef unsigned short ushort_t;
typedef __attribute__((ext_vector_type(8))) short bf16x8;
typedef __attribute__((ext_vector_type(4))) float f32x4;

__device__ __forceinline__ ushort_t f2bf(float f) {
    union { float f; unsigned i; } v; v.f = f;
    unsigned r = v.i + 0x7FFFu + ((v.i >> 16) & 1u);   // RNE
    return (ushort_t)(r >> 16);
}
__device__ __forceinline__ float bf2f(ushort_t u) {
    union { unsigned i; float f; } v; v.i = ((unsigned)u) << 16; return v.f;
}

#define GLD_LDS16(gp, lp) \
    __builtin_amdgcn_global_load_lds((const __attribute__((address_space(1))) void*)(gp), \
                                     (__attribute__((address_space(3))) void*)(lp), 16, 0, 0)

__device__ __forceinline__ int esrc(const int* ei, int f32mode, int e) {
    return f32mode ? ei[e] : ei[2 * e];
}
__device__ __forceinline__ int edst(const int* ei, int f32mode, int e) {
    return f32mode ? ei[N_EDGES + e] : ei[2 * N_EDGES + 2 * e];
}

// ---------------- K1: W2 transpose + deg/cursor init + layout detect + x->bf16 ----------------
// blocks 0..255: W2 [4096][16] fp32 -> W2T bf16 [16][4096]
// blocks 256..287: deg=1 (self-loop), cursor=0
// block 288: detect int32-vs-int64 edge layout -> flag
// blocks 289..6432: x fp32 [8192][768] -> xbf bf16 (4 elems/thread)
__global__ __launch_bounds__(256) void setup1(const float* __restrict__ W2,
                                              ushort_t* __restrict__ W2T,
                                              int* __restrict__ deg, int* __restrict__ cursor,
                                              const int* __restrict__ ei, int* __restrict__ flag,
                                              const float* __restrict__ x,
                                              ushort_t* __restrict__ xbf) {
    int b = blockIdx.x, t = threadIdx.x;
    if (b < 256) {
        int idx = b * 256 + t;                 // 65536
        int c = idx & 15, k = idx >> 4;
        W2T[c * HIDDEN + k] = f2bf(W2[idx]);
    } else if (b < 288) {
        int i = (b - 256) * 256 + t;           // 8192
        deg[i] = 1;
        cursor[i] = 0;
    } else if (b == 288) {
        // int32 layout: odd words are real edge values (not all zero over 4096 samples).
        // int64 layout: odd words are high halves of values < 8192 -> all zero.
        __shared__ int sv[256];
        int v = 0;
        for (int e = t; e < 4096; e += 256) v |= ei[2 * e + 1];
        sv[t] = v;
        __syncthreads();
        for (int off = 128; off > 0; off >>= 1) {
            if (t < off) sv[t] |= sv[t + off];
            __syncthreads();
        }
        if (t == 0) *flag = (sv[0] != 0) ? 1 : 0;
    } else {
        long i = (long)(b - 289) * 256 + t;    // 1572864 float4s
        float4 v = ((const float4*)x)[i];
        ushort4 r = { f2bf(v.x), f2bf(v.y), f2bf(v.z), f2bf(v.w) };
        ((ushort4*)xbf)[i] = r;
    }
}

// ---------------- K2: W1 transpose + degree count ----------------
__global__ __launch_bounds__(256) void setup2(const float* __restrict__ W1,
                                              ushort_t* __restrict__ W1T,
                                              const int* __restrict__ ei, int* __restrict__ deg,
                                              const int* __restrict__ flag) {
    int b = blockIdx.x, t = threadIdx.x;
    if (b < 3072) {
        __shared__ ushort_t tile[32][33];
        int n0 = (b & 127) * 32, k0 = (b >> 7) * 32;
        int tx = t & 31, ty = t >> 5;          // ty: 0..7
        #pragma unroll
        for (int j = 0; j < 4; j++) {
            int k = ty * 4 + j;
            tile[k][tx] = f2bf(W1[(k0 + k) * HIDDEN + n0 + tx]);
        }
        __syncthreads();
        #pragma unroll
        for (int j = 0; j < 4; j++) {
            int n = ty * 4 + j;
            W1T[(n0 + n) * IN_DIM + k0 + tx] = tile[tx][n];
        }
    } else {
        int e = (b - 3072) * 256 + t;          // 65536
        int f = *flag;
        atomicAdd(&deg[edst(ei, f, e)], 1);
    }
}

// exclusive scan of (deg-1) over 8192 nodes; also dinv = rsqrt(deg)
__global__ __launch_bounds__(1024) void scan_offs(const int* __restrict__ deg,
                                                  int* __restrict__ offs,
                                                  float* __restrict__ dinv) {
    __shared__ int part[1024];
    int t = threadIdx.x;
    int base = t * 8;
    int c[8]; int s = 0;
    #pragma unroll
    for (int j = 0; j < 8; j++) {
        int d = deg[base + j];
        dinv[base + j] = rsqrtf((float)d);
        c[j] = d - 1;
        s += c[j];
    }
    part[t] = s;
    __syncthreads();
    for (int off = 1; off < 1024; off <<= 1) {
        int v = part[t];
        int add = (t >= off) ? part[t - off] : 0;
        __syncthreads();
        part[t] = v + add;
        __syncthreads();
    }
    int run = part[t] - s;   // exclusive base
    #pragma unroll
    for (int j = 0; j < 8; j++) { offs[base + j] = run; run += c[j]; }
}

__global__ __launch_bounds__(256) void scatter_edges(const int* __restrict__ ei,
                                                     const int* __restrict__ offs,
                                                     int* __restrict__ cursor,
                                                     int* __restrict__ elist,
                                                     const int* __restrict__ flag) {
    int e = blockIdx.x * 256 + threadIdx.x;            // 65536
    int f = *flag;
    int s = esrc(ei, f, e), d = edst(ei, f, e);
    int p = atomicAdd(&cursor[d], 1);
    elist[offs[d] + p] = s;
}

// 3 waves per node (256 feats each = ushort4/lane); edge loop unrolled x4 for MLP.
__global__ __launch_bounds__(192) void aggregate(const ushort_t* __restrict__ xbf,
                                                 const int* __restrict__ offs,
                                                 const int* __restrict__ deg,
                                                 const int* __restrict__ elist,
                                                 const float* __restrict__ dinv,
                                                 ushort_t* __restrict__ xagg) {
    int w = threadIdx.x >> 6, l = threadIdx.x & 63;
    int d = blockIdx.x;
    int fo = w * 256 + l * 4;                          // feature offset
    float wd = dinv[d];
    ushort4 sv = *(const ushort4*)(xbf + (long)d * IN_DIM + fo);
    float a0 = wd * bf2f(sv.x), a1 = wd * bf2f(sv.y);
    float a2 = wd * bf2f(sv.z), a3 = wd * bf2f(sv.w);
    int cnt = deg[d] - 1, base = offs[d];
    int j = 0;
    for (; j + 4 <= cnt; j += 4) {
        int s0 = elist[base + j], s1 = elist[base + j + 1];
        int s2 = elist[base + j + 2], s3 = elist[base + j + 3];
        float w0 = dinv[s0], w1 = dinv[s1], w2 = dinv[s2], w3 = dinv[s3];
        ushort4 v0 = *(const ushort4*)(xbf + (long)s0 * IN_DIM + fo);
        ushort4 v1 = *(const ushort4*)(xbf + (long)s1 * IN_DIM + fo);
        ushort4 v2 = *(const ushort4*)(xbf + (long)s2 * IN_DIM + fo);
        ushort4 v3 = *(const ushort4*)(xbf + (long)s3 * IN_DIM + fo);
        a0 = fmaf(w0, bf2f(v0.x), a0); a1 = fmaf(w0, bf2f(v0.y), a1);
        a2 = fmaf(w0, bf2f(v0.z), a2); a3 = fmaf(w0, bf2f(v0.w), a3);
        a0 = fmaf(w1, bf2f(v1.x), a0); a1 = fmaf(w1, bf2f(v1.y), a1);
        a2 = fmaf(w1, bf2f(v1.z), a2); a3 = fmaf(w1, bf2f(v1.w), a3);
        a0 = fmaf(w2, bf2f(v2.x), a0); a1 = fmaf(w2, bf2f(v2.y), a1);
        a2 = fmaf(w2, bf2f(v2.z), a2); a3 = fmaf(w2, bf2f(v2.w), a3);
        a0 = fmaf(w3, bf2f(v3.x), a0); a1 = fmaf(w3, bf2f(v3.y), a1);
        a2 = fmaf(w3, bf2f(v3.z), a2); a3 = fmaf(w3, bf2f(v3.w), a3);
    }
    for (; j < cnt; j++) {
        int s = elist[base + j];
        float ws = dinv[s];
        ushort4 v = *(const ushort4*)(xbf + (long)s * IN_DIM + fo);
        a0 = fmaf(ws, bf2f(v.x), a0); a1 = fmaf(ws, bf2f(v.y), a1);
        a2 = fmaf(ws, bf2f(v.z), a2); a3 = fmaf(ws, bf2f(v.w), a3);
    }
    ushort4 r = { f2bf(a0 * wd), f2bf(a1 * wd), f2bf(a2 * wd), f2bf(a3 * wd) };
    *(ushort4*)(xagg + (long)d * IN_DIM + fo) = r;
}

// ---------------- fused GEMM1 + ReLU + partial GEMM2 (32 slabs) ----------------
__global__ __launch_bounds__(256) void gemm1_fused(const ushort_t* __restrict__ A,   // xagg bf16
                                                   const ushort_t* __restrict__ Bt,  // W1T bf16
                                                   const float* __restrict__ b1,
                                                   const ushort_t* __restrict__ W2T, // bf16 [16][4096]
                                                   float* __restrict__ part) {       // [32][8192][16]
    __shared__ char smem[40960];
    ushort_t* ldsA = (ushort_t*)smem;              // 128x32 bf16 = 8 KB
    ushort_t* ldsB = (ushort_t*)(smem + 8192);     // 8 KB
    int bx = blockIdx.x & 31;          // n tile  (4096/128 = 32)
    int by = blockIdx.x >> 5;          // m tile  (8192/128 = 64)
    int m0 = by * 128, n0 = bx * 128;
    int t = threadIdx.x;
    int w = t >> 6, l = t & 63;
    int wm = w & 1, wn = w >> 1;
    int q = l >> 4, lm = l & 15;

    f32x4 acc[4][4] = {};

    const ushort_t* Ag = A + (long)m0 * IN_DIM;
    const ushort_t* Bg = Bt + (long)n0 * IN_DIM;

    for (int ks = 0; ks < IN_DIM; ks += 32) {
        __syncthreads();
        #pragma unroll
        for (int i = 0; i < 2; i++) {
            int L = i * 256 + t;
            int row = L >> 2, c16 = L & 3;
            GLD_LDS16(Ag + row * IN_DIM + ks + c16 * 8, ldsA + (i * 256 + w * 64) * 8);
            GLD_LDS16(Bg + row * IN_DIM + ks + c16 * 8, ldsB + (i * 256 + w * 64) * 8);
        }
        __syncthreads();

        bf16x8 af[4], bfr[4];
        #pragma unroll
        for (int mt = 0; mt < 4; mt++)
            af[mt] = *(const bf16x8*)(ldsA + (wm * 64 + mt * 16 + lm) * 32 + q * 8);
        #pragma unroll
        for (int nt = 0; nt < 4; nt++)
            bfr[nt] = *(const bf16x8*)(ldsB + (wn * 64 + nt * 16 + lm) * 32 + q * 8);
        #pragma unroll
        for (int mt = 0; mt < 4; mt++)
            #pragma unroll
            for (int nt = 0; nt < 4; nt++)
                acc[mt][nt] = __builtin_amdgcn_mfma_f32_16x16x32_bf16(af[mt], bfr[nt], acc[mt][nt], 0, 0, 0);
    }

    // ---- epilogue: bias+ReLU, C-layout -> A-layout via LDS, x W2T slice ----
    __syncthreads();   // all waves done reading staging LDS before overwrite
    const int RP = 80;                                   // padded row (16B-aligned stride)
    ushort_t* myhl = (ushort_t*)smem + w * 64 * RP;      // per-wave 64x80 bf16 = 10 KB

    float bias[4];
    #pragma unroll
    for (int nt = 0; nt < 4; nt++) bias[nt] = b1[n0 + wn * 64 + nt * 16 + lm];

    #pragma unroll
    for (int mt = 0; mt < 4; mt++) {
        #pragma unroll
        for (int nt = 0; nt < 4; nt++) {
            #pragma unroll
            for (int r = 0; r < 4; r++) {
                float v = acc[mt][nt][r] + bias[nt];
                v = v > 0.0f ? v : 0.0f;
                // C layout: row_local = mt*16 + q*4 + r, col_local = nt*16 + lm
                myhl[(mt * 16 + q * 4 + r) * RP + nt * 16 + lm] = f2bf(v);
            }
        }
    }
    // no barrier: each wave reads only its own slab

    f32x4 acc2[4] = {};
    #pragma unroll
    for (int kk = 0; kk < 2; kk++) {
        bf16x8 bf2 = *(const bf16x8*)(W2T + (long)lm * HIDDEN + n0 + wn * 64 + kk * 32 + q * 8);
        #pragma unroll
        for (int mt = 0; mt < 4; mt++) {
            bf16x8 a2 = *(const bf16x8*)(myhl + (mt * 16 + lm) * RP + kk * 32 + q * 8);
            acc2[mt] = __builtin_amdgcn_mfma_f32_16x16x32_bf16(a2, bf2, acc2[mt], 0, 0, 0);
        }
    }

    // ---- merge wn=0/wn=1 partials through LDS (17-padded, conflict-free) ----
    float* psum = (float*)smem;                          // [2][64][17] fp32 = 8.7 KB
    __syncthreads();                                     // myhl reads done
    if (wn == 1) {
        #pragma unroll
        for (int mt = 0; mt < 4; mt++)
            #pragma unroll
            for (int r = 0; r < 4; r++)
                psum[(wm * 64 + mt * 16 + q * 4 + r) * 17 + lm] = acc2[mt][r];
    }
    __syncthreads();
    if (wn == 0) {
        float* pslab = part + ((long)bx * N_NODES + m0 + wm * 64) * N_CLASSES;
        #pragma unroll
        for (int mt = 0; mt < 4; mt++)
            #pragma unroll
            for (int r = 0; r < 4; r++) {
                float v = acc2[mt][r] + psum[(wm * 64 + mt * 16 + q * 4 + r) * 17 + lm];
                pslab[(mt * 16 + q * 4 + r) * N_CLASSES + lm] = v;
            }
    }
}

// ---------------- reduce 32 slabs + b2 + log_softmax ----------------
__global__ __launch_bounds__(256) void reduce_softmax(const float* __restrict__ part,
                                                      const float* __restrict__ b2,
                                                      float* __restrict__ out) {
    int t = threadIdx.x;
    int row = blockIdx.x * 16 + (t >> 4);
    int cls = t & 15;
    float v = b2[cls];
    #pragma unroll
    for (int s = 0; s < 32; s++)
        v += part[((long)s * N_NODES + row) * N_CLASSES + cls];
    float mx = v;
    #pragma unroll
    for (int off = 1; off < 16; off <<= 1)
        mx = fmaxf(mx, __shfl_xor(mx, off, 64));
    float e = __expf(v - mx);
    float sm = e;
    #pragma unroll
    for (int off = 1; off < 16; off <<= 1)
        sm += __shfl_xor(sm, off, 64);
    out[(long)row * N_CLASSES + cls] = v - mx - __logf(sm);
}

// ---------------- launch ----------------

extern "C" void kernel_launch(void* const* d_in, const int* in_sizes, int n_in,
                              void* d_out, int out_size, void* d_ws, size_t ws_size,
                              hipStream_t stream) {
    const float* x  = (const float*)d_in[0];
    const int*   ei = (const int*)d_in[1];
    const float* W1 = (const float*)d_in[2];
    const float* b1 = (const float*)d_in[3];
    const float* W2 = (const float*)d_in[4];
    const float* b2 = (const float*)d_in[5];
    float* out = (float*)d_out;
    char* ws = (char*)d_ws;

    float*    part = (float*)(ws);                           // 32*8192*16*4 = 16777216
    ushort_t* xagg = (ushort_t*)(ws + 16777216);             // 8192*768*2   = 12582912
    ushort_t* xbf  = (ushort_t*)(ws + 29360128);             // 8192*768*2   = 12582912
    ushort_t* W1T  = (ushort_t*)(ws + 41943040);             // 4096*768*2   =  6291456
    ushort_t* W2T  = (ushort_t*)(ws + 48234496);             // 16*4096*2    =   131072
    int*      deg    = (int*)(ws + 48365568);                // 8192*4
    float*    dinv   = (float*)(ws + 48398336);              // 8192*4
    int*      offs   = (int*)(ws + 48431104);                // 8192*4
    int*      cursor = (int*)(ws + 48463872);                // 8192*4
    int*      elist  = (int*)(ws + 48496640);                // 65536*4
    int*      flag   = (int*)(ws + 48758784);                // 4

    setup1<<<6433, 256, 0, stream>>>(W2, W2T, deg, cursor, ei, flag, x, xbf);
    setup2<<<3328, 256, 0, stream>>>(W1, W1T, ei, deg, flag);
    scan_offs<<<1, 1024, 0, stream>>>(deg, offs, dinv);
    scatter_edges<<<N_EDGES / 256, 256, 0, stream>>>(ei, offs, cursor, elist, flag);
    aggregate<<<N_NODES, 192, 0, stream>>>(xbf, offs, deg, elist, dinv, xagg);
    gemm1_fused<<<(N_NODES / 128) * (HIDDEN / 128), 256, 0, stream>>>(xagg, W1T, b1, W2T, part);
    reduce_softmax<<<N_NODES / 16, 256, 0, stream>>>(part, b2, out);
}